// Round 1
// baseline (31.507 us; speedup 1.0000x reference)
//
#include <hip/hip_runtime.h>

// Problem constants (from reference)
#define B_    2
#define H1_   64
#define W1_   96
#define H2_   64
#define W2_   96
#define HW_   (H1_ * W1_)        // 6144, also H2*W2
#define KWIN  81                  // 9x9 lookup window
#define CORR_ELEMS (B_ * KWIN * H1_ * W1_)        // 995328
#define UP_ELEMS   (B_ * 2 * (8*H1_) * (8*W1_))   // 1572864
#define UP_THREADS (B_ * H1_ * 8 * (8*W1_))       // 786432 (n,h,r,wc) pairs cover both channels

// ---------------------------------------------------------------------------
// corr kernel: one thread per output element of corr[b, k, i, j]
//   k = p*9 + q ; sample at (x = cx + p - 4, y = cy + q - 4)
//   bilinear, zero padding, per-corner validity (unclipped coords)
// ---------------------------------------------------------------------------
__global__ __launch_bounds__(256) void corr_kernel(const float* __restrict__ cost,
                                                   const float* __restrict__ coords,
                                                   float* __restrict__ out) {
    int o = blockIdx.x * 256 + threadIdx.x;          // grid sized exactly
    int j = o % W1_;
    int t = o / W1_;
    int i = t % H1_; t /= H1_;
    int k = t % KWIN;
    int b = t / KWIN;

    int p = k / 9;      // x-offset index
    int q = k % 9;      // y-offset index

    // coords: [B, 2, H1, W1], ch0 = x, ch1 = y
    int cbase = (b * 2 * H1_ + i) * W1_ + j;
    float cx = coords[cbase];
    float cy = coords[cbase + HW_];

    float xf = floorf(cx), yf = floorf(cy);
    float wx = cx - xf,   wy = cy - yf;
    int xi = (int)xf + (p - 4);
    int yi = (int)yf + (q - 4);

    int n = (b * H1_ + i) * W1_ + j;                 // which cost map
    const float* __restrict__ cm = cost + (size_t)n * (H2_ * W2_);

    bool vx0 = (xi >= 0) && (xi < W2_);
    bool vx1 = (xi + 1 >= 0) && (xi + 1 < W2_);
    bool vy0 = (yi >= 0) && (yi < H2_);
    bool vy1 = (yi + 1 >= 0) && (yi + 1 < H2_);

    float v00 = (vx0 && vy0) ? cm[yi * W2_ + xi]           : 0.0f;
    float v10 = (vx1 && vy0) ? cm[yi * W2_ + xi + 1]       : 0.0f;
    float v01 = (vx0 && vy1) ? cm[(yi + 1) * W2_ + xi]     : 0.0f;
    float v11 = (vx1 && vy1) ? cm[(yi + 1) * W2_ + xi + 1] : 0.0f;

    float val = (1.0f - wx) * (1.0f - wy) * v00
              +         wx  * (1.0f - wy) * v10
              + (1.0f - wx) *         wy  * v01
              +         wx  *         wy  * v11;

    out[o] = val;
}

// ---------------------------------------------------------------------------
// convex upsample kernel: one thread per (n, h, r, wc) computing both channels
//   out[n, c, h*8+r, w*8+s] = (8/sum) * sum_k exp(mask[n, k*64+r*8+s, h, w]-mx)
//                                        * flow[n, c, h+di-1, w+dj-1]  (zero pad)
//   k = di*3 + dj
// ---------------------------------------------------------------------------
__global__ __launch_bounds__(256) void upsample_kernel(const float* __restrict__ flow,
                                                       const float* __restrict__ mask,
                                                       float* __restrict__ out) {
    int tid = blockIdx.x * 256 + threadIdx.x;        // grid sized exactly
    int wc = tid % (8 * W1_);                        // 0..767
    int t  = tid / (8 * W1_);
    int r  = t % 8; t /= 8;
    int h  = t % H1_;
    int n  = t / H1_;
    int w  = wc >> 3;
    int s  = wc & 7;

    // mask: [B, 576, H1, W1]; channel = k*64 + r*8 + s
    int mbase = (n * 576 + r * 8 + s) * HW_ + h * W1_ + w;
    float mv[9];
#pragma unroll
    for (int k = 0; k < 9; ++k) mv[k] = mask[mbase + k * 64 * HW_];

    float mmax = mv[0];
#pragma unroll
    for (int k = 1; k < 9; ++k) mmax = fmaxf(mmax, mv[k]);
    float sum = 0.0f;
#pragma unroll
    for (int k = 0; k < 9; ++k) { mv[k] = __expf(mv[k] - mmax); sum += mv[k]; }

    const float* __restrict__ f0p = flow + (size_t)(n * 2 + 0) * HW_;
    const float* __restrict__ f1p = flow + (size_t)(n * 2 + 1) * HW_;

    float acc0 = 0.0f, acc1 = 0.0f;
#pragma unroll
    for (int di = 0; di < 3; ++di) {
#pragma unroll
        for (int dj = 0; dj < 3; ++dj) {
            int k = di * 3 + dj;
            int hh = h + di - 1, ww = w + dj - 1;
            bool ok = (hh >= 0) && (hh < H1_) && (ww >= 0) && (ww < W1_);
            float fv0 = ok ? f0p[hh * W1_ + ww] : 0.0f;
            float fv1 = ok ? f1p[hh * W1_ + ww] : 0.0f;
            acc0 += mv[k] * fv0;
            acc1 += mv[k] * fv1;
        }
    }
    float scale = 8.0f / sum;

    // out (up part): [B, 2, 512, 768]
    int obase = ((n * 2 + 0) * (8 * H1_) + h * 8 + r) * (8 * W1_) + wc;
    out[obase] = acc0 * scale;
    out[obase + (8 * H1_) * (8 * W1_)] = acc1 * scale;
}

extern "C" void kernel_launch(void* const* d_in, const int* in_sizes, int n_in,
                              void* d_out, int out_size, void* d_ws, size_t ws_size,
                              hipStream_t stream) {
    const float* cost   = (const float*)d_in[0];   // [12288, 1, 64, 96]
    const float* coords = (const float*)d_in[1];   // [2, 2, 64, 96]
    const float* flow   = (const float*)d_in[2];   // [2, 2, 64, 96]
    const float* mask   = (const float*)d_in[3];   // [2, 576, 64, 96]
    float* out = (float*)d_out;                    // corr (995328) ++ up_flow (1572864)

    corr_kernel<<<CORR_ELEMS / 256, 256, 0, stream>>>(cost, coords, out);
    upsample_kernel<<<UP_THREADS / 256, 256, 0, stream>>>(flow, mask, out + CORR_ELEMS);
}

// Round 2
// 16.698 us; speedup vs baseline: 1.8869x; 1.8869x over previous
//
#include <hip/hip_runtime.h>

// Problem constants (from reference)
#define B_    2
#define H1_   64
#define W1_   96
#define H2_   64
#define W2_   96
#define HW_   (H1_ * W1_)          // 6144, also H2*W2
#define KWIN  81                   // 9x9 lookup window
#define CORR_ELEMS (B_ * KWIN * HW_)              // 995328
#define UP_HW      (8 * H1_ * 8 * W1_)            // 512*768

#define CORR_PIX    (B_ * HW_)                    // 12288 pixels
#define CORR_BLOCKS (CORR_PIX / 64)               // 192  (1 wave per block)
#define UP_THREADS  (B_ * H1_ * 8 * W1_)          // 98304 (n,h,r,w); 8 s per thread
#define UP_BLOCKS   (UP_THREADS / 64)             // 1536
#define TOT_BLOCKS  (CORR_BLOCKS + UP_BLOCKS)     // 1728

// ---------------------------------------------------------------------------
// Fused kernel, 64-thread (1-wave) blocks.
//  blocks [0, CORR_BLOCKS)           : corr — one thread per pixel, 81 outputs
//  blocks [CORR_BLOCKS, TOT_BLOCKS)  : convex upsample — one thread per
//                                      (n,h,r,w), 8 s-values, both channels
// ---------------------------------------------------------------------------
__global__ __launch_bounds__(64) void fused_kernel(const float* __restrict__ cost,
                                                   const float* __restrict__ coords,
                                                   const float* __restrict__ flow,
                                                   const float* __restrict__ mask,
                                                   float* __restrict__ out) {
    if (blockIdx.x < CORR_BLOCKS) {
        // ---------------- corr ----------------
        int m = blockIdx.x * 64 + threadIdx.x;       // pixel id in [0, 12288)
        int b = m / HW_;
        int rem = m - b * HW_;                       // i*96 + j

        float cx = coords[b * 2 * HW_ + rem];
        float cy = coords[b * 2 * HW_ + HW_ + rem];
        float xf = floorf(cx), yf = floorf(cy);
        float wx = cx - xf,   wy = cy - yf;
        int xi0 = (int)xf - 4;
        int yi0 = (int)yf - 4;

        const float* __restrict__ cm = cost + (size_t)m * HW_;   // map n == m

        // 10x10 patch in registers, zero-masked (padding_mode='zeros'),
        // loads clamped so addresses are always in-bounds.
        float P[10][10];
#pragma unroll
        for (int r = 0; r < 10; ++r) {
            int y  = yi0 + r;
            bool vy = (y >= 0) & (y < H2_);
            int yc = min(max(y, 0), H2_ - 1);
            const float* rowp = cm + yc * W2_;
#pragma unroll
            for (int c = 0; c < 10; ++c) {
                int x  = xi0 + c;
                bool vx = (x >= 0) & (x < W2_);
                int xc = min(max(x, 0), W2_ - 1);
                float v = rowp[xc];
                P[r][c] = (vx & vy) ? v : 0.0f;
            }
        }

        float w00 = (1.0f - wx) * (1.0f - wy);
        float w10 = wx * (1.0f - wy);
        float w01 = (1.0f - wx) * wy;
        float w11 = wx * wy;

        size_t obase = (size_t)b * KWIN * HW_ + rem;
#pragma unroll
        for (int p = 0; p < 9; ++p) {
#pragma unroll
            for (int q = 0; q < 9; ++q) {
                float val = w00 * P[q][p]     + w10 * P[q][p + 1]
                          + w01 * P[q + 1][p] + w11 * P[q + 1][p + 1];
                out[obase + (size_t)(p * 9 + q) * HW_] = val;   // coalesced per k
            }
        }
    } else {
        // ---------------- convex upsample ----------------
        int t = (blockIdx.x - CORR_BLOCKS) * 64 + threadIdx.x;  // [0, 98304)
        int w = t % W1_;
        int u = t / W1_;
        int r = u % 8; u /= 8;
        int h = u % H1_;
        int n = u / H1_;

        // mask: [B, 576, H1, W1]; channel = k*64 + r*8 + s
        const float* __restrict__ mp = mask + ((size_t)n * 576 + r * 8) * HW_ + h * W1_ + w;
        float mv[9][8];
#pragma unroll
        for (int k = 0; k < 9; ++k)
#pragma unroll
            for (int s = 0; s < 8; ++s)
                mv[k][s] = mp[(size_t)(k * 64 + s) * HW_];      // coalesced in w

        float scale[8];
#pragma unroll
        for (int s = 0; s < 8; ++s) {
            float mx = mv[0][s];
#pragma unroll
            for (int k = 1; k < 9; ++k) mx = fmaxf(mx, mv[k][s]);
            float sum = 0.0f;
#pragma unroll
            for (int k = 0; k < 9; ++k) { mv[k][s] = __expf(mv[k][s] - mx); sum += mv[k][s]; }
            scale[s] = 8.0f / sum;
        }

        const float* __restrict__ f0p = flow + (size_t)n * 2 * HW_;
        const float* __restrict__ f1p = f0p + HW_;
        float a0[8], a1[8];
#pragma unroll
        for (int s = 0; s < 8; ++s) { a0[s] = 0.0f; a1[s] = 0.0f; }

#pragma unroll
        for (int di = 0; di < 3; ++di) {
#pragma unroll
            for (int dj = 0; dj < 3; ++dj) {
                int k = di * 3 + dj;
                int hh = h + di - 1, ww = w + dj - 1;
                bool ok = (hh >= 0) & (hh < H1_) & (ww >= 0) & (ww < W1_);
                float fv0 = ok ? f0p[hh * W1_ + ww] : 0.0f;
                float fv1 = ok ? f1p[hh * W1_ + ww] : 0.0f;
#pragma unroll
                for (int s = 0; s < 8; ++s) {
                    a0[s] += mv[k][s] * fv0;
                    a1[s] += mv[k][s] * fv1;
                }
            }
        }

        float* outU = out + CORR_ELEMS;
        size_t ob = ((size_t)(n * 2 + 0) * (8 * H1_) + h * 8 + r) * (8 * W1_) + (size_t)w * 8;
        float4 c0a = make_float4(a0[0] * scale[0], a0[1] * scale[1], a0[2] * scale[2], a0[3] * scale[3]);
        float4 c0b = make_float4(a0[4] * scale[4], a0[5] * scale[5], a0[6] * scale[6], a0[7] * scale[7]);
        float4 c1a = make_float4(a1[0] * scale[0], a1[1] * scale[1], a1[2] * scale[2], a1[3] * scale[3]);
        float4 c1b = make_float4(a1[4] * scale[4], a1[5] * scale[5], a1[6] * scale[6], a1[7] * scale[7]);
        *(float4*)(outU + ob)              = c0a;
        *(float4*)(outU + ob + 4)          = c0b;
        *(float4*)(outU + ob + UP_HW)      = c1a;
        *(float4*)(outU + ob + UP_HW + 4)  = c1b;
    }
}

extern "C" void kernel_launch(void* const* d_in, const int* in_sizes, int n_in,
                              void* d_out, int out_size, void* d_ws, size_t ws_size,
                              hipStream_t stream) {
    const float* cost   = (const float*)d_in[0];   // [12288, 1, 64, 96]
    const float* coords = (const float*)d_in[1];   // [2, 2, 64, 96]
    const float* flow   = (const float*)d_in[2];   // [2, 2, 64, 96]
    const float* mask   = (const float*)d_in[3];   // [2, 576, 64, 96]
    float* out = (float*)d_out;                    // corr (995328) ++ up_flow (1572864)

    fused_kernel<<<TOT_BLOCKS, 64, 0, stream>>>(cost, coords, flow, mask, out);
}